// Round 5
// baseline (293.717 us; speedup 1.0000x reference)
//
#include <hip/hip_runtime.h>

#define DIM 1024
#define D4  (DIM / 4)

typedef float vfloat4 __attribute__((ext_vector_type(4)));  // native vec for nontemporal builtin

static __device__ __forceinline__ float4 abs_max4(float4 m, float4 v) {
    m.x = fmaxf(m.x, fabsf(v.x)); m.y = fmaxf(m.y, fabsf(v.y));
    m.z = fmaxf(m.z, fabsf(v.z)); m.w = fmaxf(m.w, fabsf(v.w));
    return m;
}

// ---------------------------------------------------------------------------
// Pass 1: per-tier abs-max of (tw * ts), tiers 1..3, single launch.
// Round-5 changes vs round-4 (which ran at 2.5 TB/s, VGPR=20 => compiler
// serialized the loads):
//   - no min-waves launch bound -> register allocator free to keep loads live
//   - 8 named loads -> 8 named accumulators per iteration (8-deep MLP)
//   - contiguous chunk per block (sequential 32 KB steps, DRAM-friendly)
// Every element a thread touches shares column (start+t) & 255, so the ts
// multiply hoists out of the loop bit-exactly (f32 rounding is monotone, max
// commutes with multiply-by-nonneg-constant).
// ---------------------------------------------------------------------------
__global__ __launch_bounds__(256) void absmax3_kernel(
    const float4* __restrict__ tw1, const float4* __restrict__ ts1, long n1,
    const float4* __restrict__ tw2, const float4* __restrict__ ts2, long n2,
    const float4* __restrict__ tw3, const float4* __restrict__ ts3, long n3,
    int b1, int b2, unsigned* __restrict__ amax)
{
    __shared__ float smax[4];
    int bid = blockIdx.x;
    const float4 *tw, *ts; long n4; int blo, bhi; unsigned* out;
    if (bid < b1)      { tw = tw1; ts = ts1; n4 = n1; blo = 0;  bhi = b1;        out = amax + 0; }
    else if (bid < b2) { tw = tw2; ts = ts2; n4 = n2; blo = b1; bhi = b2;        out = amax + 1; }
    else               { tw = tw3; ts = ts3; n4 = n3; blo = b2; bhi = gridDim.x; out = amax + 2; }

    int  nb    = bhi - blo;
    long chunk = (n4 + nb - 1) / nb;
    long start = (long)(bid - blo) * chunk;
    long end   = start + chunk; if (end > n4) end = n4;
    int  t     = threadIdx.x;

    float4 m0 = {0,0,0,0}, m1 = {0,0,0,0}, m2 = {0,0,0,0}, m3 = {0,0,0,0};
    float4 m4 = {0,0,0,0}, m5 = {0,0,0,0}, m6 = {0,0,0,0}, m7 = {0,0,0,0};

    long base = start;
    for (; base + 2048 <= end; base += 2048) {      // 8 x 256 float4 = 32 KB/block/iter
        float4 p0 = tw[base +    0 + t];
        float4 p1 = tw[base +  256 + t];
        float4 p2 = tw[base +  512 + t];
        float4 p3 = tw[base +  768 + t];
        float4 p4 = tw[base + 1024 + t];
        float4 p5 = tw[base + 1280 + t];
        float4 p6 = tw[base + 1536 + t];
        float4 p7 = tw[base + 1792 + t];
        m0 = abs_max4(m0, p0); m1 = abs_max4(m1, p1);
        m2 = abs_max4(m2, p2); m3 = abs_max4(m3, p3);
        m4 = abs_max4(m4, p4); m5 = abs_max4(m5, p5);
        m6 = abs_max4(m6, p6); m7 = abs_max4(m7, p7);
    }
    for (long i = base + t; i < end; i += 256)      // tail, preserves i & 255
        m0 = abs_max4(m0, tw[i]);

    m0 = abs_max4(m0, m1); m2 = abs_max4(m2, m3);
    m4 = abs_max4(m4, m5); m6 = abs_max4(m6, m7);
    m0 = abs_max4(m0, m2); m4 = abs_max4(m4, m6);
    m0 = abs_max4(m0, m4);

    float4 s = ts[(start + t) & (D4 - 1)];          // loop-invariant column quad
    float m = fmaxf(fmaxf(m0.x * fabsf(s.x), m0.y * fabsf(s.y)),
                    fmaxf(m0.z * fabsf(s.z), m0.w * fabsf(s.w)));

    for (int off = 32; off > 0; off >>= 1)
        m = fmaxf(m, __shfl_down(m, off));
    if ((threadIdx.x & 63) == 0) smax[threadIdx.x >> 6] = m;
    __syncthreads();
    if (threadIdx.x == 0) {
        float bm = fmaxf(fmaxf(smax[0], smax[1]), fmaxf(smax[2], smax[3]));
        atomicMax(out, __float_as_uint(bm));
    }
}

// ---------------------------------------------------------------------------
// Pass 2 (unchanged from round 4): gather + on-the-fly fake-quant. One wave
// per token (wave-uniform tier branch), 4 tokens/block, 4 independent float4
// loads per lane. IEEE div + rintf match numpy; nontemporal output stores.
// ---------------------------------------------------------------------------
__global__ __launch_bounds__(256) void gather_quant_kernel(
    const int* __restrict__ ids, int n_tokens,
    const float* __restrict__ tw0, const float* __restrict__ tw1,
    const float* __restrict__ tw2, const float* __restrict__ tw3,
    const float* __restrict__ ts0, const float* __restrict__ ts1,
    const float* __restrict__ ts2, const float* __restrict__ ts3,
    const unsigned* __restrict__ amax, float* __restrict__ out)
{
    int sub  = threadIdx.x >> 6;
    int lane = threadIdx.x & 63;
    int token = blockIdx.x * 4 + sub;
    if (token >= n_tokens) return;
    int id = ids[token];

    const float* tw; const float* ts;
    float maxval = 1.f; unsigned am = 0; bool quant = true;
    if (id < 256)        { tw = tw0 + (long)id * DIM;           ts = ts0; quant = false; }
    else if (id < 2048)  { tw = tw1 + (long)(id - 256) * DIM;   ts = ts1; maxval = 127.f; am = amax[0]; }
    else if (id < 16384) { tw = tw2 + (long)(id - 2048) * DIM;  ts = ts2; maxval = 31.f;  am = amax[1]; }
    else                 { tw = tw3 + (long)(id - 16384) * DIM; ts = ts3; maxval = 7.f;   am = amax[2]; }

    const float4* twv = (const float4*)tw;
    const float4* tsv = (const float4*)ts;

    float4 v0 = twv[lane +   0], v1 = twv[lane +  64];
    float4 v2 = twv[lane + 128], v3 = twv[lane + 192];
    float4 s0 = tsv[lane +   0], s1 = tsv[lane +  64];
    float4 s2 = tsv[lane + 128], s3 = tsv[lane + 192];

    float scale = fmaxf(__uint_as_float(am), 1e-8f) / maxval;

    float4 vv[4] = {v0, v1, v2, v3};
    float4 ss[4] = {s0, s1, s2, s3};
    float* outp = out + (long)token * DIM;
    #pragma unroll
    for (int j = 0; j < 4; ++j) {
        vfloat4 x;
        x.x = vv[j].x * ss[j].x; x.y = vv[j].y * ss[j].y;
        x.z = vv[j].z * ss[j].z; x.w = vv[j].w * ss[j].w;
        if (quant) {
            x.x = fminf(fmaxf(rintf(x.x / scale), -maxval), maxval) * scale;
            x.y = fminf(fmaxf(rintf(x.y / scale), -maxval), maxval) * scale;
            x.z = fminf(fmaxf(rintf(x.z / scale), -maxval), maxval) * scale;
            x.w = fminf(fmaxf(rintf(x.w / scale), -maxval), maxval) * scale;
        }
        __builtin_nontemporal_store(x, (vfloat4*)outp + lane + 64 * j);
    }
}

extern "C" void kernel_launch(void* const* d_in, const int* in_sizes, int n_in,
                              void* d_out, int out_size, void* d_ws, size_t ws_size,
                              hipStream_t stream) {
    const int*   ids = (const int*)d_in[0];
    const float* tw0 = (const float*)d_in[1];
    const float* tw1 = (const float*)d_in[2];
    const float* tw2 = (const float*)d_in[3];
    const float* tw3 = (const float*)d_in[4];
    const float* ts0 = (const float*)d_in[5];
    const float* ts1 = (const float*)d_in[6];
    const float* ts2 = (const float*)d_in[7];
    const float* ts3 = (const float*)d_in[8];
    float* out = (float*)d_out;

    unsigned* amax = (unsigned*)d_ws;    // 3 entries: tiers 1..3
    (void)hipMemsetAsync(d_ws, 0, 3 * sizeof(unsigned), stream);

    long n1 = (long)in_sizes[2] / 4;     // float4 counts
    long n2 = (long)in_sizes[3] / 4;
    long n3 = (long)in_sizes[4] / 4;
    long N  = n1 + n2 + n3;

    const int G = 2048;                  // 8 blocks/CU, fully resident
    int b1 = (int)((n1 * G + N - 1) / N); if (b1 < 1) b1 = 1;
    int b2 = b1 + (int)((n2 * G) / N);    if (b2 <= b1) b2 = b1 + 1;
    if (b2 >= G) b2 = G - 1;

    absmax3_kernel<<<G, 256, 0, stream>>>(
        (const float4*)tw1, (const float4*)ts1, n1,
        (const float4*)tw2, (const float4*)ts2, n2,
        (const float4*)tw3, (const float4*)ts3, n3,
        b1, b2, amax);

    int n_tokens = in_sizes[0];          // 16384
    gather_quant_kernel<<<(n_tokens + 3) / 4, 256, 0, stream>>>(
        ids, n_tokens, tw0, tw1, tw2, tw3, ts0, ts1, ts2, ts3, amax, out);
}

// Round 6
// 284.439 us; speedup vs baseline: 1.0326x; 1.0326x over previous
//
#include <hip/hip_runtime.h>

#define DIM 1024
#define D4  (DIM / 4)

typedef float vfloat4 __attribute__((ext_vector_type(4)));  // native vec for nontemporal builtins

static __device__ __forceinline__ vfloat4 nt_load4(const vfloat4* p) {
    return __builtin_nontemporal_load(p);   // global_load_dwordx4 ... nt : coherent, no-allocate
}
static __device__ __forceinline__ vfloat4 abs_max4(vfloat4 m, vfloat4 v) {
    m.x = fmaxf(m.x, fabsf(v.x)); m.y = fmaxf(m.y, fabsf(v.y));
    m.z = fmaxf(m.z, fabsf(v.z)); m.w = fmaxf(m.w, fabsf(v.w));
    return m;
}

// ---------------------------------------------------------------------------
// Pass 1: per-tier abs-max of (tw * ts), tiers 1..3, single launch.
// Round-6 change: NONTEMPORAL loads for the tw streams. Theory: the harness
// re-poisons 555 MB before every launch, leaving L3 fully dirty; normal loads
// that miss L3 allocate a line -> evict dirty victim -> hidden writeback to
// HBM (~100 MB), doubling actual HBM traffic. nt loads are coherent (still
// hit the dirty restored lines) but don't allocate on miss -> no writebacks.
// Everything else (chunked slabs, 8 named accumulators, hoisted ts multiply
// — bit-exact since f32 rounding is monotone) kept from round 5.
// ---------------------------------------------------------------------------
__global__ __launch_bounds__(256) void absmax3_kernel(
    const vfloat4* __restrict__ tw1, const vfloat4* __restrict__ ts1, long n1,
    const vfloat4* __restrict__ tw2, const vfloat4* __restrict__ ts2, long n2,
    const vfloat4* __restrict__ tw3, const vfloat4* __restrict__ ts3, long n3,
    int b1, int b2, unsigned* __restrict__ amax)
{
    __shared__ float smax[4];
    int bid = blockIdx.x;
    const vfloat4 *tw, *ts; long n4; int blo, bhi; unsigned* out;
    if (bid < b1)      { tw = tw1; ts = ts1; n4 = n1; blo = 0;  bhi = b1;        out = amax + 0; }
    else if (bid < b2) { tw = tw2; ts = ts2; n4 = n2; blo = b1; bhi = b2;        out = amax + 1; }
    else               { tw = tw3; ts = ts3; n4 = n3; blo = b2; bhi = gridDim.x; out = amax + 2; }

    int  nb    = bhi - blo;
    long chunk = (n4 + nb - 1) / nb;
    long start = (long)(bid - blo) * chunk;
    long end   = start + chunk; if (end > n4) end = n4;
    int  t     = threadIdx.x;

    vfloat4 m0 = {0,0,0,0}, m1 = {0,0,0,0}, m2 = {0,0,0,0}, m3 = {0,0,0,0};
    vfloat4 m4 = {0,0,0,0}, m5 = {0,0,0,0}, m6 = {0,0,0,0}, m7 = {0,0,0,0};

    long base = start;
    for (; base + 2048 <= end; base += 2048) {      // 8 x 256 float4 = 32 KB/block/iter
        vfloat4 p0 = nt_load4(tw + base +    0 + t);
        vfloat4 p1 = nt_load4(tw + base +  256 + t);
        vfloat4 p2 = nt_load4(tw + base +  512 + t);
        vfloat4 p3 = nt_load4(tw + base +  768 + t);
        vfloat4 p4 = nt_load4(tw + base + 1024 + t);
        vfloat4 p5 = nt_load4(tw + base + 1280 + t);
        vfloat4 p6 = nt_load4(tw + base + 1536 + t);
        vfloat4 p7 = nt_load4(tw + base + 1792 + t);
        m0 = abs_max4(m0, p0); m1 = abs_max4(m1, p1);
        m2 = abs_max4(m2, p2); m3 = abs_max4(m3, p3);
        m4 = abs_max4(m4, p4); m5 = abs_max4(m5, p5);
        m6 = abs_max4(m6, p6); m7 = abs_max4(m7, p7);
    }
    for (long i = base + t; i < end; i += 256)      // tail, preserves i & 255
        m0 = abs_max4(m0, nt_load4(tw + i));

    m0 = abs_max4(m0, m1); m2 = abs_max4(m2, m3);
    m4 = abs_max4(m4, m5); m6 = abs_max4(m6, m7);
    m0 = abs_max4(m0, m2); m4 = abs_max4(m4, m6);
    m0 = abs_max4(m0, m4);

    vfloat4 s = ts[(start + t) & (D4 - 1)];         // loop-invariant column quad
    float m = fmaxf(fmaxf(m0.x * fabsf(s.x), m0.y * fabsf(s.y)),
                    fmaxf(m0.z * fabsf(s.z), m0.w * fabsf(s.w)));

    for (int off = 32; off > 0; off >>= 1)
        m = fmaxf(m, __shfl_down(m, off));
    if ((threadIdx.x & 63) == 0) smax[threadIdx.x >> 6] = m;
    __syncthreads();
    if (threadIdx.x == 0) {
        float bm = fmaxf(fmaxf(smax[0], smax[1]), fmaxf(smax[2], smax[3]));
        atomicMax(out, __float_as_uint(bm));
    }
}

// ---------------------------------------------------------------------------
// Pass 2: gather + on-the-fly fake-quant. One wave per token (wave-uniform
// tier branch), 4 tokens/block, 4 independent nt float4 loads per lane.
// IEEE div + rintf (half-even) match numpy; nontemporal output stores.
// ---------------------------------------------------------------------------
__global__ __launch_bounds__(256) void gather_quant_kernel(
    const int* __restrict__ ids, int n_tokens,
    const float* __restrict__ tw0, const float* __restrict__ tw1,
    const float* __restrict__ tw2, const float* __restrict__ tw3,
    const float* __restrict__ ts0, const float* __restrict__ ts1,
    const float* __restrict__ ts2, const float* __restrict__ ts3,
    const unsigned* __restrict__ amax, float* __restrict__ out)
{
    int sub  = threadIdx.x >> 6;
    int lane = threadIdx.x & 63;
    int token = blockIdx.x * 4 + sub;
    if (token >= n_tokens) return;
    int id = ids[token];

    const float* tw; const float* ts;
    float maxval = 1.f; unsigned am = 0; bool quant = true;
    if (id < 256)        { tw = tw0 + (long)id * DIM;           ts = ts0; quant = false; }
    else if (id < 2048)  { tw = tw1 + (long)(id - 256) * DIM;   ts = ts1; maxval = 127.f; am = amax[0]; }
    else if (id < 16384) { tw = tw2 + (long)(id - 2048) * DIM;  ts = ts2; maxval = 31.f;  am = amax[1]; }
    else                 { tw = tw3 + (long)(id - 16384) * DIM; ts = ts3; maxval = 7.f;   am = amax[2]; }

    const vfloat4* twv = (const vfloat4*)tw;
    const vfloat4* tsv = (const vfloat4*)ts;

    vfloat4 v0 = nt_load4(twv + lane +   0), v1 = nt_load4(twv + lane +  64);
    vfloat4 v2 = nt_load4(twv + lane + 128), v3 = nt_load4(twv + lane + 192);
    vfloat4 s0 = tsv[lane +   0], s1 = tsv[lane +  64];
    vfloat4 s2 = tsv[lane + 128], s3 = tsv[lane + 192];

    float scale = fmaxf(__uint_as_float(am), 1e-8f) / maxval;

    vfloat4 vv[4] = {v0, v1, v2, v3};
    vfloat4 ss[4] = {s0, s1, s2, s3};
    float* outp = out + (long)token * DIM;
    #pragma unroll
    for (int j = 0; j < 4; ++j) {
        vfloat4 x = vv[j] * ss[j];
        if (quant) {
            x.x = fminf(fmaxf(rintf(x.x / scale), -maxval), maxval) * scale;
            x.y = fminf(fmaxf(rintf(x.y / scale), -maxval), maxval) * scale;
            x.z = fminf(fmaxf(rintf(x.z / scale), -maxval), maxval) * scale;
            x.w = fminf(fmaxf(rintf(x.w / scale), -maxval), maxval) * scale;
        }
        __builtin_nontemporal_store(x, (vfloat4*)outp + lane + 64 * j);
    }
}

extern "C" void kernel_launch(void* const* d_in, const int* in_sizes, int n_in,
                              void* d_out, int out_size, void* d_ws, size_t ws_size,
                              hipStream_t stream) {
    const int*   ids = (const int*)d_in[0];
    const float* tw0 = (const float*)d_in[1];
    const float* tw1 = (const float*)d_in[2];
    const float* tw2 = (const float*)d_in[3];
    const float* tw3 = (const float*)d_in[4];
    const float* ts0 = (const float*)d_in[5];
    const float* ts1 = (const float*)d_in[6];
    const float* ts2 = (const float*)d_in[7];
    const float* ts3 = (const float*)d_in[8];
    float* out = (float*)d_out;

    unsigned* amax = (unsigned*)d_ws;    // 3 entries: tiers 1..3
    (void)hipMemsetAsync(d_ws, 0, 3 * sizeof(unsigned), stream);

    long n1 = (long)in_sizes[2] / 4;     // float4 counts
    long n2 = (long)in_sizes[3] / 4;
    long n3 = (long)in_sizes[4] / 4;
    long N  = n1 + n2 + n3;

    const int G = 2048;                  // 8 blocks/CU, fully resident
    int b1 = (int)((n1 * G + N - 1) / N); if (b1 < 1) b1 = 1;
    int b2 = b1 + (int)((n2 * G) / N);    if (b2 <= b1) b2 = b1 + 1;
    if (b2 >= G) b2 = G - 1;

    absmax3_kernel<<<G, 256, 0, stream>>>(
        (const vfloat4*)tw1, (const vfloat4*)ts1, n1,
        (const vfloat4*)tw2, (const vfloat4*)ts2, n2,
        (const vfloat4*)tw3, (const vfloat4*)ts3, n3,
        b1, b2, amax);

    int n_tokens = in_sizes[0];          // 16384
    gather_quant_kernel<<<(n_tokens + 3) / 4, 256, 0, stream>>>(
        ids, n_tokens, tw0, tw1, tw2, tw3, ts0, ts1, ts2, ts3, amax, out);
}